// Round 4
// baseline (168.527 us; speedup 1.0000x reference)
//
#include <hip/hip_runtime.h>
#include <math.h>

// Problem constants
#define B_   64
#define T_   512
#define D_   96
#define TY_  512
#define H_   4
#define DK_  32
#define E_   128
#define P_   2
#define L_   64
#define HID_ 128

// Workspace layout (float offsets)
#define WS_OB2P  1024      // 8*64 : ob2 partials (const-half of ow, 8 slices)
#define WS_PN    2048      // 64b*8c*8hp*96f = 393216 : partial numerators
#define WS_PD    395264    // 393216 : partial denominators

// ---------------------------------------------------------------------------
// Kernel SP (fused prep + scores + exp + pool): grid (8 t-chunks, 64 b), 256 thr.
// Prologue (redundant per block, k_w/q_w hit L2):
//   qm[p,e'] = query[p,:] @ q_w + q_b
//   w2q[e,hp] = sum_dk k_w[e,h*32+dk]*qm[p,h*32+dk]/sqrt(32);  bq likewise
// Phase A: w[t,hp] = exp(emb(t) . w2q[:,hp] + bq[hp])   (no max-sub: |s|<~20)
// Phase B: num[hp,f] += w*M*X ; den[hp,f] += w*M  over the 64-t chunk
// Epilogue (b==0 blocks only): ob2 partial slice c -> ws  (xa 2nd half == 1)
// ---------------------------------------------------------------------------
__global__ __launch_bounds__(256) void kspool(
    const float* __restrict__ tsteps, const float* __restrict__ te_w,
    const float* __restrict__ te_b,   const float* __restrict__ X,
    const float* __restrict__ M,      const float* __restrict__ query,
    const float* __restrict__ q_w,    const float* __restrict__ q_b,
    const float* __restrict__ k_w,    const float* __restrict__ k_b,
    const float* __restrict__ ow,     float* __restrict__ ws)
{
    const int c = blockIdx.x, b = blockIdx.y, tid = threadIdx.x;
    __shared__ float qm[P_ * E_];
    __shared__ float w2q_s[E_ * 8];
    __shared__ float tw_s[E_], tb_s[E_], bq_s[8];
    __shared__ float w_s[64 * 8];
    __shared__ float red[96 * 17];  // stride 17: no bank conflicts
    __shared__ float obp2[4][64];

    // ---- Prologue: fused q/k weights ----
    {
        int p = tid >> 7, ep = tid & 127;
        float acc = q_b[ep];
        #pragma unroll 4
        for (int e = 0; e < E_; ++e)
            acc += query[p * E_ + e] * q_w[e * E_ + ep];
        qm[p * E_ + ep] = acc;
    }
    if (tid < E_) { tw_s[tid] = te_w[tid]; tb_s[tid] = te_b[tid]; }
    __syncthreads();
    const float rs = 0.17677669529663687f;  // 1/sqrt(32)
    #pragma unroll
    for (int i = 0; i < 4; ++i) {
        int idx = tid + i * 256;
        int e = idx >> 3, hp = idx & 7, h = hp >> 1, p = hp & 1;
        float acc = 0.f;
        #pragma unroll
        for (int dk = 0; dk < DK_; ++dk)
            acc += k_w[e * E_ + h * DK_ + dk] * qm[p * E_ + h * DK_ + dk];
        w2q_s[idx] = acc * rs;
    }
    if (tid < 8) {
        int hp = tid, h = hp >> 1, p = hp & 1;
        float acc = 0.f;
        #pragma unroll
        for (int dk = 0; dk < DK_; ++dk)
            acc += k_b[h * DK_ + dk] * qm[p * E_ + h * DK_ + dk];
        bq_s[hp] = acc * rs;
    }
    __syncthreads();

    // ---- Phase A: thread = (t in chunk, hp-pair) ----
    {
        const int t = tid & 63, hpg = tid >> 6, hp0 = hpg * 2;
        const float tv = tsteps[b * T_ + c * 64 + t];
        float a0 = 0.f, a1 = 0.f;
        #pragma unroll 4
        for (int e = 0; e < E_; ++e) {
            float v = tv * tw_s[e] + tb_s[e];
            if ((e & 3) == 0) v = __sinf(v);
            float2 w = *(const float2*)&w2q_s[e * 8 + hp0];
            a0 += v * w.x;
            a1 += v * w.y;
        }
        w_s[t * 8 + hp0]     = __expf(a0 + bq_s[hp0]);
        w_s[t * 8 + hp0 + 1] = __expf(a1 + bq_s[hp0 + 1]);
    }
    __syncthreads();

    // ---- Phase B: 2 t-slices x 128 fid (96 active) ----
    const int fid = tid & 127, slice = tid >> 7;
    float num[8] = {0.f, 0.f, 0.f, 0.f, 0.f, 0.f, 0.f, 0.f};
    float den[8] = {0.f, 0.f, 0.f, 0.f, 0.f, 0.f, 0.f, 0.f};
    if (fid < 96) {
        #pragma unroll 4
        for (int i = 0; i < 32; ++i) {
            int tl = slice + 2 * i;
            size_t base = ((size_t)(b * T_ + c * 64 + tl)) * D_ + fid;
            float m = M[base], x = X[base];
            float mx = m * x;
            const float* wr = w_s + tl * 8;
            #pragma unroll
            for (int hp = 0; hp < 8; ++hp) {
                num[hp] += wr[hp] * mx;
                den[hp] += wr[hp] * m;
            }
        }
    }
    __syncthreads();
    if (slice == 1 && fid < 96) {
        #pragma unroll
        for (int hp = 0; hp < 8; ++hp) {
            red[fid * 17 + hp]     = num[hp];
            red[fid * 17 + 8 + hp] = den[hp];
        }
    }
    __syncthreads();
    if (slice == 0 && fid < 96) {
        float* pN = ws + WS_PN + ((size_t)((b * 8 + c) * 8)) * 96;
        float* pD = ws + WS_PD + ((size_t)((b * 8 + c) * 8)) * 96;
        #pragma unroll
        for (int hp = 0; hp < 8; ++hp) {
            pN[hp * 96 + fid] = num[hp] + red[fid * 17 + hp];
            pD[hp * 96 + fid] = den[hp] + red[fid * 17 + 8 + hp];
        }
    }

    // ---- Epilogue (b==0 only): ob2 partial slice c over 48 (h,j) pairs ----
    if (b == 0) {
        int sub = tid >> 6, l = tid & 63;
        float acc = 0.f;
        #pragma unroll
        for (int k = 0; k < 12; ++k) {
            int hj = c * 48 + sub * 12 + k;
            int h = hj / 96, j = hj - h * 96;
            acc += ow[(size_t)(h * 2 * D_ + D_ + j) * L_ + l];
        }
        obp2[sub][l] = acc;
        __syncthreads();
        if (sub == 0)
            ws[WS_OB2P + c * 64 + l] = obp2[0][l] + obp2[1][l] + obp2[2][l] + obp2[3][l];
    }
}

// ---------------------------------------------------------------------------
// Kernel DF (fused coeffs + decoder): 512 blocks (b = bx>>3), 256 threads.
// Prologue (redundant x8 per b): reduce pool partials -> xa -> coeffs ->
//   a0[j] = b1[j] + c0 . w1[:,j] ; a1[j] = c1 . w1[:,j]
// Body: h[j,pos] = relu(a0[j] + y[pos]*a1[j]) staged in LDS (32 KB);
//   out[pos,d] = sum_j h[j,pos]*w2[j,d] + b2[d]   (4 pos x 6 d per thread)
// ---------------------------------------------------------------------------
__global__ __launch_bounds__(256) void kdecf(
    const float* __restrict__ yts, const float* __restrict__ ow,
    const float* __restrict__ w1,  const float* __restrict__ b1,
    const float* __restrict__ ob,  const float* __restrict__ w2,
    const float* __restrict__ b2,  const float* __restrict__ ws,
    float* __restrict__ out)
{
    __shared__ float xa_s[8 * 96];
    __shared__ float cfp[4][2][64];     // coeff partials per h
    __shared__ float cf_s[2][64];
    __shared__ float abp[2][2][128];    // a0/a1 partials (2 l-slices)
    __shared__ float a0_s[HID_], a1_s[HID_];
    __shared__ float y_s[64];
    __shared__ float h_s[HID_ * 64];    // 32 KB
    const int tid = threadIdx.x;
    const int bx = blockIdx.x;
    const int b = bx >> 3;
    const int posb = bx * 64;           // flat position base (b*512 + ty0)

    if (tid < 64) y_s[tid] = yts[posb + tid];

    // phase 0: reduce pool partials -> xa
    for (int flat = tid; flat < 8 * 96; flat += 256) {
        int hp = flat / 96, f = flat - hp * 96;
        float n = 0.f, d = 0.f;
        #pragma unroll
        for (int c = 0; c < 8; ++c) {
            n += ws[WS_PN + ((size_t)((b * 8 + c) * 8 + hp)) * 96 + f];
            d += ws[WS_PD + ((size_t)((b * 8 + c) * 8 + hp)) * 96 + f];
        }
        xa_s[flat] = n / d;
    }
    __syncthreads();

    // phase 1: coeff GEMV, 2 items/thread over (h,p,l)
    #pragma unroll
    for (int it = 0; it < 2; ++it) {
        int idx = tid + it * 256;
        int h = idx >> 7, p = (idx >> 6) & 1, l = idx & 63;
        const float* xr = xa_s + (h * 2 + p) * 96;
        const float* owr = ow + (size_t)(h * 2 * D_) * L_ + l;
        float acc = 0.f;
        #pragma unroll 4
        for (int f = 0; f < 96; ++f)
            acc += xr[f] * owr[(size_t)f * L_];
        cfp[h][p][l] = acc;
    }
    __syncthreads();

    // phase 2: combine coeff partials + ob + ob2 partials
    if (tid < 128) {
        int p = tid >> 6, l = tid & 63;
        float v = cfp[0][p][l] + cfp[1][p][l] + cfp[2][p][l] + cfp[3][p][l] + ob[l];
        #pragma unroll
        for (int g = 0; g < 8; ++g) v += ws[WS_OB2P + g * 64 + l];
        cf_s[p][l] = v;
    }
    __syncthreads();

    // phase 3: a0/a1 GEMV, thread = (l-slice, j)
    {
        int s = tid >> 7, j = tid & 127;
        float a0 = 0.f, a1 = 0.f;
        #pragma unroll 4
        for (int li = 0; li < 32; ++li) {
            int l = s * 32 + li;
            float wv = w1[l * HID_ + j];
            a0 += cf_s[0][l] * wv;
            a1 += cf_s[1][l] * wv;
        }
        abp[s][0][j] = a0;
        abp[s][1][j] = a1;
    }
    __syncthreads();

    // phase 4: combine -> a0_s/a1_s
    if (tid < 128) {
        a0_s[tid] = abp[0][0][tid] + abp[1][0][tid] + b1[tid];
    } else {
        int j = tid - 128;
        a1_s[j] = abp[0][1][j] + abp[1][1][j];
    }
    __syncthreads();

    // phase 5: h staging
    #pragma unroll 4
    for (int r = 0; r < 32; ++r) {
        int flat = r * 256 + tid;       // = j*64 + pos
        int j = flat >> 6, pos = flat & 63;
        h_s[flat] = fmaxf(0.f, a0_s[j] + y_s[pos] * a1_s[j]);
    }
    __syncthreads();

    // phase 6: out GEMM, 4 pos x 6 d per thread
    const int pg = tid >> 4, dg = tid & 15;
    const int p0 = pg * 4, d0 = dg * 6;
    float acc[4][6];
    #pragma unroll
    for (int pp = 0; pp < 4; ++pp)
        #pragma unroll
        for (int dd = 0; dd < 6; ++dd) acc[pp][dd] = 0.f;

    #pragma unroll 2
    for (int j = 0; j < HID_; ++j) {
        float4 h4 = *(const float4*)&h_s[j * 64 + p0];
        const float* wr = w2 + j * D_ + d0;
        float wv[6];
        #pragma unroll
        for (int dd = 0; dd < 6; ++dd) wv[dd] = wr[dd];
        const float hv[4] = {h4.x, h4.y, h4.z, h4.w};
        #pragma unroll
        for (int pp = 0; pp < 4; ++pp)
            #pragma unroll
            for (int dd = 0; dd < 6; ++dd)
                acc[pp][dd] += hv[pp] * wv[dd];
    }

    float bv[6];
    #pragma unroll
    for (int dd = 0; dd < 6; ++dd) bv[dd] = b2[d0 + dd];
    #pragma unroll
    for (int pp = 0; pp < 4; ++pp) {
        size_t obase = ((size_t)(posb + p0 + pp)) * D_ + d0;
        #pragma unroll
        for (int dd = 0; dd < 6; ++dd) out[obase + dd] = acc[pp][dd] + bv[dd];
    }
}

// ---------------------------------------------------------------------------
extern "C" void kernel_launch(void* const* d_in, const int* in_sizes, int n_in,
                              void* d_out, int out_size, void* d_ws, size_t ws_size,
                              hipStream_t stream)
{
    const float* timesteps = (const float*)d_in[0];
    const float* X         = (const float*)d_in[1];
    const float* M         = (const float*)d_in[2];
    const float* yts       = (const float*)d_in[3];
    const float* te_w      = (const float*)d_in[4];
    const float* te_b      = (const float*)d_in[5];
    const float* query     = (const float*)d_in[6];
    const float* q_w       = (const float*)d_in[7];
    const float* q_b       = (const float*)d_in[8];
    const float* k_w       = (const float*)d_in[9];
    const float* k_b       = (const float*)d_in[10];
    const float* ow        = (const float*)d_in[11];
    const float* ob        = (const float*)d_in[12];
    const float* w1        = (const float*)d_in[13];
    const float* b1        = (const float*)d_in[14];
    const float* w2        = (const float*)d_in[15];
    const float* b2        = (const float*)d_in[16];
    float* out = (float*)d_out;
    float* ws  = (float*)d_ws;

    kspool<<<dim3(8, B_), 256, 0, stream>>>(timesteps, te_w, te_b, X, M,
                                            query, q_w, q_b, k_w, k_b, ow, ws);
    kdecf<<<(B_ * TY_) / 64, 256, 0, stream>>>(yts, ow, w1, b1, ob, w2, b2, ws, out);
}

// Round 5
// 163.075 us; speedup vs baseline: 1.0334x; 1.0334x over previous
//
#include <hip/hip_runtime.h>
#include <math.h>

// Problem constants
#define B_   64
#define T_   512
#define D_   96
#define TY_  512
#define H_   4
#define DK_  32
#define E_   128
#define P_   2
#define L_   64
#define HID_ 128

// Workspace layout (float offsets)
#define WS_OB2P  1024      // 8*64 : ob2 partials (const-half of ow, 8 slices)
#define WS_PN    2048      // 64b*8c*8hp*96f = 393216 : partial numerators
#define WS_PD    395264    // 393216 : partial denominators
#define WS_AB    788480    // 64*2*128 : decoder a0/a1

// ---------------------------------------------------------------------------
// Kernel SP (fused prep + scores + exp + pool): grid (8 t-chunks, 64 b), 256 thr.
//   qm[p,e'] = query[p,:] @ q_w + q_b    (redundant per block, L2-hot)
//   w2q[e,hp] = sum_dk k_w[e,h*32+dk]*qm[p,h*32+dk]/sqrt(32);  bq likewise
// Phase A: w[t,hp] = exp(emb(t) . w2q[:,hp] + bq[hp])   (no max-sub: |s|<~20)
// Phase B: num[hp,f] += w*M*X ; den[hp,f] += w*M  over the 64-t chunk
// Epilogue (b==0 blocks): ob2 partial slice c (xa 2nd half == 1 -> bias fold)
// ---------------------------------------------------------------------------
__global__ __launch_bounds__(256) void kspool(
    const float* __restrict__ tsteps, const float* __restrict__ te_w,
    const float* __restrict__ te_b,   const float* __restrict__ X,
    const float* __restrict__ M,      const float* __restrict__ query,
    const float* __restrict__ q_w,    const float* __restrict__ q_b,
    const float* __restrict__ k_w,    const float* __restrict__ k_b,
    const float* __restrict__ ow,     float* __restrict__ ws)
{
    const int c = blockIdx.x, b = blockIdx.y, tid = threadIdx.x;
    __shared__ float qm[P_ * E_];
    __shared__ float w2q_s[E_ * 8];
    __shared__ float tw_s[E_], tb_s[E_], bq_s[8];
    __shared__ float w_s[64 * 8];
    __shared__ float red[96 * 17];  // stride 17: no bank conflicts
    __shared__ float obp2[4][64];

    // ---- Prologue: fused q/k weights ----
    {
        int p = tid >> 7, ep = tid & 127;
        float acc = q_b[ep];
        #pragma unroll 4
        for (int e = 0; e < E_; ++e)
            acc += query[p * E_ + e] * q_w[e * E_ + ep];
        qm[p * E_ + ep] = acc;
    }
    if (tid < E_) { tw_s[tid] = te_w[tid]; tb_s[tid] = te_b[tid]; }
    __syncthreads();
    const float rs = 0.17677669529663687f;  // 1/sqrt(32)
    #pragma unroll
    for (int i = 0; i < 4; ++i) {
        int idx = tid + i * 256;
        int e = idx >> 3, hp = idx & 7, h = hp >> 1, p = hp & 1;
        float acc = 0.f;
        #pragma unroll
        for (int dk = 0; dk < DK_; ++dk)
            acc += k_w[e * E_ + h * DK_ + dk] * qm[p * E_ + h * DK_ + dk];
        w2q_s[idx] = acc * rs;
    }
    if (tid < 8) {
        int hp = tid, h = hp >> 1, p = hp & 1;
        float acc = 0.f;
        #pragma unroll
        for (int dk = 0; dk < DK_; ++dk)
            acc += k_b[h * DK_ + dk] * qm[p * E_ + h * DK_ + dk];
        bq_s[hp] = acc * rs;
    }
    __syncthreads();

    // ---- Phase A: thread = (t in chunk, hp-pair) ----
    {
        const int t = tid & 63, hpg = tid >> 6, hp0 = hpg * 2;
        const float tv = tsteps[b * T_ + c * 64 + t];
        float a0 = 0.f, a1 = 0.f;
        #pragma unroll 4
        for (int e = 0; e < E_; ++e) {
            float v = tv * tw_s[e] + tb_s[e];
            if ((e & 3) == 0) v = __sinf(v);
            float2 w = *(const float2*)&w2q_s[e * 8 + hp0];
            a0 += v * w.x;
            a1 += v * w.y;
        }
        w_s[t * 8 + hp0]     = __expf(a0 + bq_s[hp0]);
        w_s[t * 8 + hp0 + 1] = __expf(a1 + bq_s[hp0 + 1]);
    }
    __syncthreads();

    // ---- Phase B: 2 t-slices x 128 fid (96 active) ----
    const int fid = tid & 127, slice = tid >> 7;
    float num[8] = {0.f, 0.f, 0.f, 0.f, 0.f, 0.f, 0.f, 0.f};
    float den[8] = {0.f, 0.f, 0.f, 0.f, 0.f, 0.f, 0.f, 0.f};
    if (fid < 96) {
        #pragma unroll 4
        for (int i = 0; i < 32; ++i) {
            int tl = slice + 2 * i;
            size_t base = ((size_t)(b * T_ + c * 64 + tl)) * D_ + fid;
            float m = M[base], x = X[base];
            float mx = m * x;
            const float* wr = w_s + tl * 8;
            #pragma unroll
            for (int hp = 0; hp < 8; ++hp) {
                num[hp] += wr[hp] * mx;
                den[hp] += wr[hp] * m;
            }
        }
    }
    __syncthreads();
    if (slice == 1 && fid < 96) {
        #pragma unroll
        for (int hp = 0; hp < 8; ++hp) {
            red[fid * 17 + hp]     = num[hp];
            red[fid * 17 + 8 + hp] = den[hp];
        }
    }
    __syncthreads();
    if (slice == 0 && fid < 96) {
        float* pN = ws + WS_PN + ((size_t)((b * 8 + c) * 8)) * 96;
        float* pD = ws + WS_PD + ((size_t)((b * 8 + c) * 8)) * 96;
        #pragma unroll
        for (int hp = 0; hp < 8; ++hp) {
            pN[hp * 96 + fid] = num[hp] + red[fid * 17 + hp];
            pD[hp * 96 + fid] = den[hp] + red[fid * 17 + 8 + hp];
        }
    }

    // ---- Epilogue (b==0 only): ob2 partial slice c over 48 (h,j) pairs ----
    if (b == 0) {
        int sub = tid >> 6, l = tid & 63;
        float acc = 0.f;
        #pragma unroll
        for (int k = 0; k < 12; ++k) {
            int hj = c * 48 + sub * 12 + k;
            int h = hj / 96, j = hj - h * 96;
            acc += ow[(size_t)(h * 2 * D_ + D_ + j) * L_ + l];
        }
        obp2[sub][l] = acc;
        __syncthreads();
        if (sub == 0)
            ws[WS_OB2P + c * 64 + l] = obp2[0][l] + obp2[1][l] + obp2[2][l] + obp2[3][l];
    }
}

// ---------------------------------------------------------------------------
// Kernel AB: partials -> xa -> coeffs -> a0/a1. 64 blocks x 256 threads.
// ---------------------------------------------------------------------------
__global__ __launch_bounds__(256) void kab(
    const float* __restrict__ ow, const float* __restrict__ w1,
    const float* __restrict__ b1, const float* __restrict__ ob,
    float* __restrict__ ws)
{
    const int b = blockIdx.x, tid = threadIdx.x;
    __shared__ float xa_s[8 * 96];
    __shared__ float cfp[4][2][64];
    __shared__ float cf_s[2][64];
    __shared__ float abp[2][2][128];

    // phase 0: reduce pool partials -> xa
    for (int flat = tid; flat < 8 * 96; flat += 256) {
        int hp = flat / 96, f = flat - hp * 96;
        float n = 0.f, d = 0.f;
        #pragma unroll
        for (int c = 0; c < 8; ++c) {
            n += ws[WS_PN + ((size_t)((b * 8 + c) * 8 + hp)) * 96 + f];
            d += ws[WS_PD + ((size_t)((b * 8 + c) * 8 + hp)) * 96 + f];
        }
        xa_s[flat] = n / d;
    }
    __syncthreads();

    // phase 1: coeff GEMV, 2 items/thread over (h,p,l)
    #pragma unroll
    for (int it = 0; it < 2; ++it) {
        int idx = tid + it * 256;
        int h = idx >> 7, p = (idx >> 6) & 1, l = idx & 63;
        const float* xr = xa_s + (h * 2 + p) * 96;
        const float* owr = ow + (size_t)(h * 2 * D_) * L_ + l;
        float acc = 0.f;
        #pragma unroll 4
        for (int f = 0; f < 96; ++f)
            acc += xr[f] * owr[(size_t)f * L_];
        cfp[h][p][l] = acc;
    }
    __syncthreads();

    // phase 2: combine coeff partials + ob + ob2 partials
    if (tid < 128) {
        int p = tid >> 6, l = tid & 63;
        float v = cfp[0][p][l] + cfp[1][p][l] + cfp[2][p][l] + cfp[3][p][l] + ob[l];
        #pragma unroll
        for (int g = 0; g < 8; ++g) v += ws[WS_OB2P + g * 64 + l];
        cf_s[p][l] = v;
    }
    __syncthreads();

    // phase 3: a0/a1 GEMV, thread = (l-slice, j)
    {
        int s = tid >> 7, j = tid & 127;
        float a0 = 0.f, a1 = 0.f;
        #pragma unroll 4
        for (int li = 0; li < 32; ++li) {
            int l = s * 32 + li;
            float wv = w1[l * HID_ + j];
            a0 += cf_s[0][l] * wv;
            a1 += cf_s[1][l] * wv;
        }
        abp[s][0][j] = a0;
        abp[s][1][j] = a1;
    }
    __syncthreads();

    // phase 4: combine + write
    if (tid < 128) {
        ws[WS_AB + b * 256 + tid] = abp[0][0][tid] + abp[1][0][tid] + b1[tid];
    } else {
        int j = tid - 128;
        ws[WS_AB + b * 256 + 128 + j] = abp[0][1][j] + abp[1][1][j];
    }
}

// ---------------------------------------------------------------------------
// Kernel D: decoder GEMM. 512 blocks (64 pos each) x 256 threads.
// w2 staged in LDS (48 KB, L2-hot). Thread = (pos = tid&63, ds = tid>>6);
// all 64 lanes of a wave share ds -> every w2_s/a0_s/a1_s read in the j-loop
// is wave-uniform (LDS broadcast, conflict-free). h recomputed per thread
// (2 VALU per 24 FMA) - no h_s round-trip.
//   out[pos, ds*24+dd] = sum_j relu(a0[j]+y[pos]*a1[j]) * w2[j, ds*24+dd]
// ---------------------------------------------------------------------------
__global__ __launch_bounds__(256) void kdec(
    const float* __restrict__ yts, const float* __restrict__ w2,
    const float* __restrict__ b2,  const float* __restrict__ ws,
    float* __restrict__ out)
{
    __shared__ float w2_s[HID_ * D_];   // 48 KB
    __shared__ float a0_s[HID_], a1_s[HID_];
    __shared__ float y_s[64];
    const int tid = threadIdx.x;
    const int posb = blockIdx.x * 64;   // flat position base (b*512 + ty0)
    const int b = posb >> 9;

    // stage w2 (12288 floats = 12 float4/thread, coalesced)
    {
        const float4* src = (const float4*)w2;
        float4* dst = (float4*)w2_s;
        #pragma unroll
        for (int i = 0; i < 12; ++i) dst[tid + i * 256] = src[tid + i * 256];
    }
    if (tid < 64) y_s[tid] = yts[posb + tid];
    if (tid >= 64 && tid < 192) {
        int j = tid - 64;
        a0_s[j] = ws[WS_AB + b * 256 + j];
        a1_s[j] = ws[WS_AB + b * 256 + 128 + j];
    }
    __syncthreads();

    const int pos = tid & 63, ds = tid >> 6;
    const float y = y_s[pos];
    const float* wrow = w2_s + ds * 24;

    float acc[24];
    #pragma unroll
    for (int dd = 0; dd < 24; ++dd) acc[dd] = 0.f;

    #pragma unroll 4
    for (int j = 0; j < HID_; ++j) {
        float h = fmaxf(0.f, a0_s[j] + y * a1_s[j]);
        const float* wr = wrow + j * D_;
        #pragma unroll
        for (int q = 0; q < 6; ++q) {
            float4 w4 = *(const float4*)(wr + q * 4);
            acc[q * 4 + 0] += h * w4.x;
            acc[q * 4 + 1] += h * w4.y;
            acc[q * 4 + 2] += h * w4.z;
            acc[q * 4 + 3] += h * w4.w;
        }
    }

    // epilogue: bias + store 24 consecutive floats (6x float4)
    float* op = out + ((size_t)(posb + pos)) * D_ + ds * 24;
    const float* bp = b2 + ds * 24;
    #pragma unroll
    for (int q = 0; q < 6; ++q) {
        float4 v;
        v.x = acc[q * 4 + 0] + bp[q * 4 + 0];
        v.y = acc[q * 4 + 1] + bp[q * 4 + 1];
        v.z = acc[q * 4 + 2] + bp[q * 4 + 2];
        v.w = acc[q * 4 + 3] + bp[q * 4 + 3];
        *(float4*)(op + q * 4) = v;
    }
}

// ---------------------------------------------------------------------------
extern "C" void kernel_launch(void* const* d_in, const int* in_sizes, int n_in,
                              void* d_out, int out_size, void* d_ws, size_t ws_size,
                              hipStream_t stream)
{
    const float* timesteps = (const float*)d_in[0];
    const float* X         = (const float*)d_in[1];
    const float* M         = (const float*)d_in[2];
    const float* yts       = (const float*)d_in[3];
    const float* te_w      = (const float*)d_in[4];
    const float* te_b      = (const float*)d_in[5];
    const float* query     = (const float*)d_in[6];
    const float* q_w       = (const float*)d_in[7];
    const float* q_b       = (const float*)d_in[8];
    const float* k_w       = (const float*)d_in[9];
    const float* k_b       = (const float*)d_in[10];
    const float* ow        = (const float*)d_in[11];
    const float* ob        = (const float*)d_in[12];
    const float* w1        = (const float*)d_in[13];
    const float* b1        = (const float*)d_in[14];
    const float* w2        = (const float*)d_in[15];
    const float* b2        = (const float*)d_in[16];
    float* out = (float*)d_out;
    float* ws  = (float*)d_ws;

    kspool<<<dim3(8, B_), 256, 0, stream>>>(timesteps, te_w, te_b, X, M,
                                            query, q_w, q_b, k_w, k_b, ow, ws);
    kab<<<B_, 256, 0, stream>>>(ow, w1, b1, ob, ws);
    kdec<<<(B_ * TY_) / 64, 256, 0, stream>>>(yts, w2, b2, ws, out);
}